// Round 2
// baseline (6810.636 us; speedup 1.0000x reference)
//
#include <hip/hip_runtime.h>

// Problem constants (match reference)
#define Bsz 8
#define Ssz 2048
#define PLM 768
#define Gd  256
#define N_WM 50000
#define E_WM 800000
#define N_F  16384   // B*S
#define E_F  131072
#define Kc   4

typedef short short8 __attribute__((ext_vector_type(8)));
typedef float f32x4 __attribute__((ext_vector_type(4)));

// RNE float -> bf16 bits
__device__ __forceinline__ unsigned short f2bf(float f) {
    union { float f; unsigned int u; } v; v.f = f;
    unsigned int r = (v.u + 0x7fffu + ((v.u >> 16) & 1u)) >> 16;
    return (unsigned short)r;
}

__device__ __forceinline__ float4 ld4(const float* __restrict__ p, int row, int rowlen, int col) {
    return *(const float4*)(p + (size_t)row * rowlen + col);
}

// ---------------------------------------------------------------------------
// scatter-add: m[dst[e]] += h[src[e]]; one wave per edge, float4 per lane
// ---------------------------------------------------------------------------
__global__ void scatter_add_kernel(const float* __restrict__ h,
                                   const int* __restrict__ src,
                                   const int* __restrict__ dst,
                                   float* __restrict__ m, int E) {
    int e = blockIdx.x * 4 + (threadIdx.x >> 6);
    if (e >= E) return;
    int lane = threadIdx.x & 63;
    int s = src[e], d = dst[e];
    float4 v = ((const float4*)(h + (size_t)s * Gd))[lane];
    float* o = m + (size_t)d * Gd + lane * 4;
    atomicAdd(o + 0, v.x);
    atomicAdd(o + 1, v.y);
    atomicAdd(o + 2, v.z);
    atomicAdd(o + 3, v.w);
}

// ---------------------------------------------------------------------------
// tmp[i] = sum_k table[token2nodepos[i,k]+2]   (table = [extra_emb; gemb])
// ---------------------------------------------------------------------------
__global__ void tmp_kernel(const float* __restrict__ gemb,
                           const float* __restrict__ extra,
                           const int* __restrict__ t2np,
                           float* __restrict__ D) {
    int i = blockIdx.x * 4 + (threadIdx.x >> 6);
    int lane = threadIdx.x & 63;
    float4 s = make_float4(0.f, 0.f, 0.f, 0.f);
#pragma unroll
    for (int k = 0; k < Kc; ++k) {
        int idx = t2np[i * Kc + k] + 2;
        const float4* row = (idx < 2) ? (const float4*)(extra + (size_t)idx * Gd)
                                      : (const float4*)(gemb + (size_t)(idx - 2) * Gd);
        float4 v = row[lane];
        s.x += v.x; s.y += v.y; s.z += v.z; s.w += v.w;
    }
    ((float4*)(D + (size_t)i * Gd))[lane] = s;
}

// ---------------------------------------------------------------------------
// row gather: F[i] = E[ids[i]]
// ---------------------------------------------------------------------------
__global__ void gather_kernel(const float* __restrict__ Ein,
                              const int* __restrict__ ids,
                              float* __restrict__ F) {
    int i = blockIdx.x * 4 + (threadIdx.x >> 6);
    int lane = threadIdx.x & 63;
    ((float4*)(F + (size_t)i * Gd))[lane] =
        ((const float4*)(Ein + (size_t)ids[i] * Gd))[lane];
}

// ---------------------------------------------------------------------------
// bf16 MFMA GEMM: C = act(Aeff @ W + b), 128x128 block tile, 4 waves, 64x64/wave
// MODE 1: A = p0[row*256+k] + p1[row*256+k]                      (h + m), K=256
// MODE 2: A = k<256 ? p0[row*256+k] : p1[row*768 + k-256]        (tmp|text), K=1024
// MODE 3: A = k<768 ? p0 : (k<1024 ? p1 : p2)                    (text|tmp|temporal), K=1280
// ---------------------------------------------------------------------------
#define TBM 128
#define TBN 128
#define TBK 64
#define LDSS 72   // LDS leading-dim stride in bf16 elems (pad 8 -> 16B-aligned rows)

template <int MODE>
__global__ __launch_bounds__(256) void mfma_gemm(
    const float* __restrict__ p0, const float* __restrict__ p1,
    const float* __restrict__ p2, const float* __restrict__ W,
    const float* __restrict__ bias, float* __restrict__ C,
    int M, int N, int K, int relu) {
    __shared__ unsigned short As[TBM * LDSS];   // [row][k]
    __shared__ unsigned short Bs[TBN * LDSS];   // [col][k]  (W transposed)

    int tid  = threadIdx.x;
    int lane = tid & 63;
    int wave = tid >> 6;
    int wm = (wave >> 1) * 64, wn = (wave & 1) * 64;
    int row0 = blockIdx.y * TBM, col0 = blockIdx.x * TBN;
    int l15 = lane & 15, l4 = lane >> 4;

    f32x4 acc[4][4];
#pragma unroll
    for (int i = 0; i < 4; ++i)
#pragma unroll
        for (int j = 0; j < 4; ++j)
            acc[i][j] = (f32x4){0.f, 0.f, 0.f, 0.f};

    for (int k0 = 0; k0 < K; k0 += TBK) {
        // ---- stage A: 128 rows x 64 k, float4 loads -> bf16 LDS ----
#pragma unroll
        for (int it = 0; it < 8; ++it) {
            int idx = it * 256 + tid;       // float4 index
            int r   = idx >> 4;             // 16 float4 per row
            int k4  = (idx & 15) * 4;
            int grow = row0 + r, gk = k0 + k4;
            float4 v = make_float4(0.f, 0.f, 0.f, 0.f);
            if (grow < M) {
                if (MODE == 1) {
                    float4 a = ld4(p0, grow, 256, gk);
                    float4 b = ld4(p1, grow, 256, gk);
                    v = make_float4(a.x + b.x, a.y + b.y, a.z + b.z, a.w + b.w);
                } else if (MODE == 2) {
                    v = (gk < 256) ? ld4(p0, grow, 256, gk)
                                   : ld4(p1, grow, 768, gk - 256);
                } else {
                    if (gk < 768)       v = ld4(p0, grow, 768, gk);
                    else if (gk < 1024) v = ld4(p1, grow, 256, gk - 768);
                    else                v = ld4(p2, grow, 256, gk - 1024);
                }
            }
            ushort4 u;
            u.x = f2bf(v.x); u.y = f2bf(v.y); u.z = f2bf(v.z); u.w = f2bf(v.w);
            *(ushort4*)(&As[r * LDSS + k4]) = u;
        }
        // ---- stage B (transpose): Bs[n][k] = W[k0+k][col0+n] ----
#pragma unroll
        for (int it = 0; it < 8; ++it) {
            int idx = it * 256 + tid;       // k-quad index
            int n   = idx & 127;
            int k4  = (idx >> 7) * 4;
            ushort4 u;
            u.x = f2bf(W[(size_t)(k0 + k4 + 0) * N + col0 + n]);
            u.y = f2bf(W[(size_t)(k0 + k4 + 1) * N + col0 + n]);
            u.z = f2bf(W[(size_t)(k0 + k4 + 2) * N + col0 + n]);
            u.w = f2bf(W[(size_t)(k0 + k4 + 3) * N + col0 + n]);
            *(ushort4*)(&Bs[n * LDSS + k4]) = u;
        }
        __syncthreads();

#pragma unroll
        for (int ks = 0; ks < TBK; ks += 32) {
            short8 af[4], bfr[4];
#pragma unroll
            for (int mi = 0; mi < 4; ++mi)
                af[mi] = *(const short8*)&As[(wm + mi * 16 + l15) * LDSS + ks + l4 * 8];
#pragma unroll
            for (int ni = 0; ni < 4; ++ni)
                bfr[ni] = *(const short8*)&Bs[(wn + ni * 16 + l15) * LDSS + ks + l4 * 8];
#pragma unroll
            for (int mi = 0; mi < 4; ++mi)
#pragma unroll
                for (int ni = 0; ni < 4; ++ni)
                    acc[mi][ni] = __builtin_amdgcn_mfma_f32_16x16x32_bf16(
                        af[mi], bfr[ni], acc[mi][ni], 0, 0, 0);
        }
        __syncthreads();
    }

    // ---- epilogue: bias (+relu), C/D layout col=lane&15, row=(lane>>4)*4+reg ----
#pragma unroll
    for (int ni = 0; ni < 4; ++ni) {
        int c = col0 + wn + ni * 16 + l15;
        float bv = bias[c];
#pragma unroll
        for (int mi = 0; mi < 4; ++mi) {
#pragma unroll
            for (int r = 0; r < 4; ++r) {
                int rr = row0 + wm + mi * 16 + l4 * 4 + r;
                if (rr < M) {
                    float v = acc[mi][ni][r] + bv;
                    if (relu) v = fmaxf(v, 0.f);
                    C[(size_t)rr * N + c] = v;
                }
            }
        }
    }
}

// ---------------------------------------------------------------------------
extern "C" void kernel_launch(void* const* d_in, const int* in_sizes, int n_in,
                              void* d_out, int out_size, void* d_ws, size_t ws_size,
                              hipStream_t stream) {
    const float* text    = (const float*)d_in[0];   // [16384, 768]
    const float* wm_x    = (const float*)d_in[1];   // [50000, 256]
    const int*   wm_ei   = (const int*)d_in[2];     // [2, 800000]
    const int*   t2np    = (const int*)d_in[3];     // [16384, 4]
    const int*   f_ids   = (const int*)d_in[4];     // [16384]
    const int*   f_ei    = (const int*)d_in[5];     // [2, 131072]
    const float* extra   = (const float*)d_in[6];   // [2, 256]
    const float* wm_W1   = (const float*)d_in[7];
    const float* wm_b1   = (const float*)d_in[8];
    const float* wm_W2   = (const float*)d_in[9];
    const float* wm_b2   = (const float*)d_in[10];
    const float* fs_W1   = (const float*)d_in[11];
    const float* fs_b1   = (const float*)d_in[12];
    const float* fs_W2   = (const float*)d_in[13];
    const float* fs_b2   = (const float*)d_in[14];
    const float* fc1_W   = (const float*)d_in[15];  // [1024, 256]
    const float* fc1_b   = (const float*)d_in[16];
    const float* fc3_W   = (const float*)d_in[17];  // [1280, 768]
    const float* fc3_b   = (const float*)d_in[18];
    float* out = (float*)d_out;                     // [16384, 768]

    // workspace layout (fp32)
    float* A  = (float*)d_ws;                 // [50000,256] m-buffer (reused)
    float* Bb = A  + (size_t)N_WM * Gd;       // [50000,256] wm h1 (reused: F, H)
    float* Cc = Bb + (size_t)N_WM * Gd;       // [50000,256] gemb (reused: E, T)
    float* D  = Cc + (size_t)N_WM * Gd;       // [16384,256] tmp

    float* F  = Bb;                           // [16384,256] gathered x
    float* H  = Bb + (size_t)N_F * Gd;        // [16384,256] fstm h1
    float* Ee = Cc;                           // [16384,256] graph_text_embed
    float* T  = Cc + (size_t)N_F * Gd;        // [16384,256] temporal

    const int* wm_src = wm_ei;
    const int* wm_dst = wm_ei + E_WM;
    const int* f_src  = f_ei;
    const int* f_dst  = f_ei + E_F;

    const size_t wm_m_bytes = (size_t)N_WM * Gd * sizeof(float);
    const size_t fs_m_bytes = (size_t)N_F * Gd * sizeof(float);

    dim3 blk(256);
    dim3 gW(Gd / TBN, (N_WM + TBM - 1) / TBM);   // 2 x 391
    dim3 gF(Gd / TBN, N_F / TBM);                // 2 x 128
    dim3 gO(PLM / TBN, N_F / TBM);               // 6 x 128

    // ===== WM layer 1 =====
    hipMemsetAsync(A, 0, wm_m_bytes, stream);
    scatter_add_kernel<<<(E_WM + 3) / 4, blk, 0, stream>>>(wm_x, wm_src, wm_dst, A, E_WM);
    mfma_gemm<1><<<gW, blk, 0, stream>>>(wm_x, A, nullptr, wm_W1, wm_b1, Bb,
                                         N_WM, Gd, Gd, 1);
    // ===== WM layer 2 =====
    hipMemsetAsync(A, 0, wm_m_bytes, stream);
    scatter_add_kernel<<<(E_WM + 3) / 4, blk, 0, stream>>>(Bb, wm_src, wm_dst, A, E_WM);
    mfma_gemm<1><<<gW, blk, 0, stream>>>(Bb, A, nullptr, wm_W2, wm_b2, Cc,
                                         N_WM, Gd, Gd, 1);
    // ===== tmp (K-slot gather-sum) =====
    tmp_kernel<<<N_F / 4, blk, 0, stream>>>(Cc, extra, t2np, D);
    // ===== fc1: E = concat(tmp, text) @ fc1_W + b =====
    mfma_gemm<2><<<gF, blk, 0, stream>>>(D, text, nullptr, fc1_W, fc1_b, Ee,
                                         N_F, Gd, Gd + PLM, 0);
    // ===== FSTM gather =====
    gather_kernel<<<N_F / 4, blk, 0, stream>>>(Ee, f_ids, F);
    // ===== FSTM layer 1 =====
    hipMemsetAsync(A, 0, fs_m_bytes, stream);
    scatter_add_kernel<<<(E_F + 3) / 4, blk, 0, stream>>>(F, f_src, f_dst, A, E_F);
    mfma_gemm<1><<<gF, blk, 0, stream>>>(F, A, nullptr, fs_W1, fs_b1, H,
                                         N_F, Gd, Gd, 1);
    // ===== FSTM layer 2 =====
    hipMemsetAsync(A, 0, fs_m_bytes, stream);
    scatter_add_kernel<<<(E_F + 3) / 4, blk, 0, stream>>>(H, f_src, f_dst, A, E_F);
    mfma_gemm<1><<<gF, blk, 0, stream>>>(H, A, nullptr, fs_W2, fs_b2, T,
                                         N_F, Gd, Gd, 1);
    // ===== fc3: out = concat(text, tmp, temporal) @ fc3_W + b =====
    mfma_gemm<3><<<gO, blk, 0, stream>>>(text, D, T, fc3_W, fc3_b, out,
                                         N_F, PLM, PLM + 2 * Gd, 0);
}

// Round 3
// 1149.478 us; speedup vs baseline: 5.9250x; 5.9250x over previous
//
#include <hip/hip_runtime.h>

// Problem constants (match reference)
#define Bsz 8
#define Ssz 2048
#define PLM 768
#define Gd  256
#define N_WM 50000
#define E_WM 800000
#define N_F  16384   // B*S
#define E_F  131072
#define Kc   4

typedef short short8 __attribute__((ext_vector_type(8)));
typedef float f32x4 __attribute__((ext_vector_type(4)));

// RNE float -> bf16 bits
__device__ __forceinline__ unsigned short f2bf(float f) {
    union { float f; unsigned int u; } v; v.f = f;
    unsigned int r = (v.u + 0x7fffu + ((v.u >> 16) & 1u)) >> 16;
    return (unsigned short)r;
}

__device__ __forceinline__ float4 ld4(const float* __restrict__ p, int row, int rowlen, int col) {
    return *(const float4*)(p + (size_t)row * rowlen + col);
}

// ---------------------------------------------------------------------------
// CSR build: histogram -> exclusive scan -> bucket fill (int atomics only)
// ---------------------------------------------------------------------------
__global__ void hist_kernel(const int* __restrict__ dst, int* __restrict__ cnt, int E) {
    int e = blockIdx.x * 256 + threadIdx.x;
    if (e < E) atomicAdd(&cnt[dst[e]], 1);
}

// single block, 256 threads: exclusive scan of cnt[0..n) -> off[0..n],
// re-init cnt[i] = off[i] (as the fill cursor)
__global__ __launch_bounds__(256) void scan_kernel(int* __restrict__ cnt,
                                                   int* __restrict__ off, int n) {
    __shared__ int base[257];
    int t = threadIdx.x;
    int chunk = (n + 255) / 256;
    int lo = t * chunk;
    int hi = lo + chunk; if (hi > n) hi = n; if (lo > n) lo = n;
    int s = 0;
    for (int i = lo; i < hi; ++i) s += cnt[i];
    base[t + 1] = s;
    __syncthreads();
    if (t == 0) {
        base[0] = 0;
        for (int j = 1; j <= 256; ++j) base[j] += base[j - 1];
    }
    __syncthreads();
    int acc = base[t];
    for (int i = lo; i < hi; ++i) {
        int c = cnt[i];
        off[i] = acc;
        cnt[i] = acc;   // cursor
        acc += c;
    }
    if (t == 255) off[n] = base[256];
}

__global__ void fill_kernel(const int* __restrict__ src, const int* __restrict__ dst,
                            int* __restrict__ cur, int* __restrict__ bucket, int E) {
    int e = blockIdx.x * 256 + threadIdx.x;
    if (e < E) {
        int p = atomicAdd(&cur[dst[e]], 1);
        bucket[p] = src[e];
    }
}

// ---------------------------------------------------------------------------
// aggregate: hm[i] = h[i] + sum_{j in CSR(i)} h[bucket[j]]   (no atomics)
// one wave per node, float4 per lane
// ---------------------------------------------------------------------------
__global__ void aggregate_kernel(const float* __restrict__ h,
                                 const int* __restrict__ off,
                                 const int* __restrict__ bucket,
                                 float* __restrict__ hm, int n) {
    int i = blockIdx.x * 4 + (threadIdx.x >> 6);
    if (i >= n) return;
    int lane = threadIdx.x & 63;
    int s0 = off[i], s1 = off[i + 1];
    float4 acc = ((const float4*)(h + (size_t)i * Gd))[lane];
    for (int j = s0; j < s1; ++j) {
        int s = bucket[j];
        float4 v = ((const float4*)(h + (size_t)s * Gd))[lane];
        acc.x += v.x; acc.y += v.y; acc.z += v.z; acc.w += v.w;
    }
    ((float4*)(hm + (size_t)i * Gd))[lane] = acc;
}

// ---------------------------------------------------------------------------
// tmp[i] = sum_k table[token2nodepos[i,k]+2]   (table = [extra_emb; gemb])
// ---------------------------------------------------------------------------
__global__ void tmp_kernel(const float* __restrict__ gemb,
                           const float* __restrict__ extra,
                           const int* __restrict__ t2np,
                           float* __restrict__ D) {
    int i = blockIdx.x * 4 + (threadIdx.x >> 6);
    int lane = threadIdx.x & 63;
    float4 s = make_float4(0.f, 0.f, 0.f, 0.f);
#pragma unroll
    for (int k = 0; k < Kc; ++k) {
        int idx = t2np[i * Kc + k] + 2;
        const float4* row = (idx < 2) ? (const float4*)(extra + (size_t)idx * Gd)
                                      : (const float4*)(gemb + (size_t)(idx - 2) * Gd);
        float4 v = row[lane];
        s.x += v.x; s.y += v.y; s.z += v.z; s.w += v.w;
    }
    ((float4*)(D + (size_t)i * Gd))[lane] = s;
}

// ---------------------------------------------------------------------------
// row gather: F[i] = E[ids[i]]
// ---------------------------------------------------------------------------
__global__ void gather_kernel(const float* __restrict__ Ein,
                              const int* __restrict__ ids,
                              float* __restrict__ F) {
    int i = blockIdx.x * 4 + (threadIdx.x >> 6);
    int lane = threadIdx.x & 63;
    ((float4*)(F + (size_t)i * Gd))[lane] =
        ((const float4*)(Ein + (size_t)ids[i] * Gd))[lane];
}

// ---------------------------------------------------------------------------
// bf16 MFMA GEMM: C = act(Aeff @ W + b), 128x128 block tile, 4 waves, 64x64/wave
// MODE 0: A = p0[row*K + k]                                      (plain)
// MODE 2: A = k<256 ? p0[row*256+k] : p1[row*768 + k-256]        (tmp|text), K=1024
// MODE 3: A = k<768 ? p0 : (k<1024 ? p1 : p2)                    (text|tmp|temporal), K=1280
// ---------------------------------------------------------------------------
#define TBM 128
#define TBN 128
#define TBK 64
#define LDSS 72   // LDS leading-dim stride in bf16 elems (pad 8 -> 16B-aligned rows)

template <int MODE>
__global__ __launch_bounds__(256) void mfma_gemm(
    const float* __restrict__ p0, const float* __restrict__ p1,
    const float* __restrict__ p2, const float* __restrict__ W,
    const float* __restrict__ bias, float* __restrict__ C,
    int M, int N, int K, int relu) {
    __shared__ unsigned short As[TBM * LDSS];   // [row][k]
    __shared__ unsigned short Bs[TBN * LDSS];   // [col][k]  (W transposed)

    int tid  = threadIdx.x;
    int lane = tid & 63;
    int wave = tid >> 6;
    int wm = (wave >> 1) * 64, wn = (wave & 1) * 64;
    int row0 = blockIdx.y * TBM, col0 = blockIdx.x * TBN;
    int l15 = lane & 15, l4 = lane >> 4;

    f32x4 acc[4][4];
#pragma unroll
    for (int i = 0; i < 4; ++i)
#pragma unroll
        for (int j = 0; j < 4; ++j)
            acc[i][j] = (f32x4){0.f, 0.f, 0.f, 0.f};

    for (int k0 = 0; k0 < K; k0 += TBK) {
        // ---- stage A: 128 rows x 64 k, float4 loads -> bf16 LDS ----
#pragma unroll
        for (int it = 0; it < 8; ++it) {
            int idx = it * 256 + tid;       // float4 index
            int r   = idx >> 4;             // 16 float4 per row
            int k4  = (idx & 15) * 4;
            int grow = row0 + r, gk = k0 + k4;
            float4 v = make_float4(0.f, 0.f, 0.f, 0.f);
            if (grow < M) {
                if (MODE == 0) {
                    v = ld4(p0, grow, K, gk);
                } else if (MODE == 2) {
                    v = (gk < 256) ? ld4(p0, grow, 256, gk)
                                   : ld4(p1, grow, 768, gk - 256);
                } else {
                    if (gk < 768)       v = ld4(p0, grow, 768, gk);
                    else if (gk < 1024) v = ld4(p1, grow, 256, gk - 768);
                    else                v = ld4(p2, grow, 256, gk - 1024);
                }
            }
            ushort4 u;
            u.x = f2bf(v.x); u.y = f2bf(v.y); u.z = f2bf(v.z); u.w = f2bf(v.w);
            *(ushort4*)(&As[r * LDSS + k4]) = u;
        }
        // ---- stage B (transpose): Bs[n][k] = W[k0+k][col0+n] ----
#pragma unroll
        for (int it = 0; it < 8; ++it) {
            int idx = it * 256 + tid;       // k-quad index
            int n   = idx & 127;
            int k4  = (idx >> 7) * 4;
            ushort4 u;
            u.x = f2bf(W[(size_t)(k0 + k4 + 0) * N + col0 + n]);
            u.y = f2bf(W[(size_t)(k0 + k4 + 1) * N + col0 + n]);
            u.z = f2bf(W[(size_t)(k0 + k4 + 2) * N + col0 + n]);
            u.w = f2bf(W[(size_t)(k0 + k4 + 3) * N + col0 + n]);
            *(ushort4*)(&Bs[n * LDSS + k4]) = u;
        }
        __syncthreads();

#pragma unroll
        for (int ks = 0; ks < TBK; ks += 32) {
            short8 af[4], bfr[4];
#pragma unroll
            for (int mi = 0; mi < 4; ++mi)
                af[mi] = *(const short8*)&As[(wm + mi * 16 + l15) * LDSS + ks + l4 * 8];
#pragma unroll
            for (int ni = 0; ni < 4; ++ni)
                bfr[ni] = *(const short8*)&Bs[(wn + ni * 16 + l15) * LDSS + ks + l4 * 8];
#pragma unroll
            for (int mi = 0; mi < 4; ++mi)
#pragma unroll
                for (int ni = 0; ni < 4; ++ni)
                    acc[mi][ni] = __builtin_amdgcn_mfma_f32_16x16x32_bf16(
                        af[mi], bfr[ni], acc[mi][ni], 0, 0, 0);
        }
        __syncthreads();
    }

    // ---- epilogue: bias (+relu), C/D layout col=lane&15, row=(lane>>4)*4+reg ----
#pragma unroll
    for (int ni = 0; ni < 4; ++ni) {
        int c = col0 + wn + ni * 16 + l15;
        float bv = bias[c];
#pragma unroll
        for (int mi = 0; mi < 4; ++mi) {
#pragma unroll
            for (int r = 0; r < 4; ++r) {
                int rr = row0 + wm + mi * 16 + l4 * 4 + r;
                if (rr < M) {
                    float v = acc[mi][ni][r] + bv;
                    if (relu) v = fmaxf(v, 0.f);
                    C[(size_t)rr * N + c] = v;
                }
            }
        }
    }
}

// ---------------------------------------------------------------------------
extern "C" void kernel_launch(void* const* d_in, const int* in_sizes, int n_in,
                              void* d_out, int out_size, void* d_ws, size_t ws_size,
                              hipStream_t stream) {
    const float* text    = (const float*)d_in[0];   // [16384, 768]
    const float* wm_x    = (const float*)d_in[1];   // [50000, 256]
    const int*   wm_ei   = (const int*)d_in[2];     // [2, 800000]
    const int*   t2np    = (const int*)d_in[3];     // [16384, 4]
    const int*   f_ids   = (const int*)d_in[4];     // [16384]
    const int*   f_ei    = (const int*)d_in[5];     // [2, 131072]
    const float* extra   = (const float*)d_in[6];   // [2, 256]
    const float* wm_W1   = (const float*)d_in[7];
    const float* wm_b1   = (const float*)d_in[8];
    const float* wm_W2   = (const float*)d_in[9];
    const float* wm_b2   = (const float*)d_in[10];
    const float* fs_W1   = (const float*)d_in[11];
    const float* fs_b1   = (const float*)d_in[12];
    const float* fs_W2   = (const float*)d_in[13];
    const float* fs_b2   = (const float*)d_in[14];
    const float* fc1_W   = (const float*)d_in[15];  // [1024, 256]
    const float* fc1_b   = (const float*)d_in[16];
    const float* fc3_W   = (const float*)d_in[17];  // [1280, 768]
    const float* fc3_b   = (const float*)d_in[18];
    float* out = (float*)d_out;                     // [16384, 768]

    // workspace layout (fp32 part)
    float* A  = (float*)d_ws;                 // [50000,256] hm buffer (reused)
    float* Bb = A  + (size_t)N_WM * Gd;       // [50000,256] wm h1 (reused: F, H)
    float* Cc = Bb + (size_t)N_WM * Gd;       // [50000,256] gemb (reused: E, T)
    float* D  = Cc + (size_t)N_WM * Gd;       // [16384,256] tmp

    float* F  = Bb;                           // [16384,256] gathered x
    float* H  = Bb + (size_t)N_F * Gd;        // [16384,256] fstm h1
    float* Ee = Cc;                           // [16384,256] graph_text_embed
    float* T  = Cc + (size_t)N_F * Gd;        // [16384,256] temporal

    // int workspace (CSR)
    int* wm_off = (int*)(D + (size_t)N_F * Gd);   // [N_WM+1]
    int* wm_cnt = wm_off + N_WM + 1;              // [N_WM]
    int* wm_bkt = wm_cnt + N_WM;                  // [E_WM]
    int* fs_off = wm_bkt + E_WM;                  // [N_F+1]
    int* fs_cnt = fs_off + N_F + 1;               // [N_F]
    int* fs_bkt = fs_cnt + N_F;                   // [E_F]

    const int* wm_src = wm_ei;
    const int* wm_dst = wm_ei + E_WM;
    const int* f_src  = f_ei;
    const int* f_dst  = f_ei + E_F;

    dim3 blk(256);
    dim3 gW(Gd / TBN, (N_WM + TBM - 1) / TBM);   // 2 x 391
    dim3 gF(Gd / TBN, N_F / TBM);                // 2 x 128
    dim3 gO(PLM / TBN, N_F / TBM);               // 6 x 128

    // ===== build CSR (once per call; reused by both layers of each GNN) =====
    hipMemsetAsync(wm_cnt, 0, N_WM * sizeof(int), stream);
    hipMemsetAsync(fs_cnt, 0, N_F * sizeof(int), stream);
    hist_kernel<<<(E_WM + 255) / 256, blk, 0, stream>>>(wm_dst, wm_cnt, E_WM);
    hist_kernel<<<(E_F + 255) / 256, blk, 0, stream>>>(f_dst, fs_cnt, E_F);
    scan_kernel<<<1, blk, 0, stream>>>(wm_cnt, wm_off, N_WM);
    scan_kernel<<<1, blk, 0, stream>>>(fs_cnt, fs_off, N_F);
    fill_kernel<<<(E_WM + 255) / 256, blk, 0, stream>>>(wm_src, wm_dst, wm_cnt, wm_bkt, E_WM);
    fill_kernel<<<(E_F + 255) / 256, blk, 0, stream>>>(f_src, f_dst, fs_cnt, fs_bkt, E_F);

    // ===== WM layer 1 =====
    aggregate_kernel<<<(N_WM + 3) / 4, blk, 0, stream>>>(wm_x, wm_off, wm_bkt, A, N_WM);
    mfma_gemm<0><<<gW, blk, 0, stream>>>(A, nullptr, nullptr, wm_W1, wm_b1, Bb,
                                         N_WM, Gd, Gd, 1);
    // ===== WM layer 2 =====
    aggregate_kernel<<<(N_WM + 3) / 4, blk, 0, stream>>>(Bb, wm_off, wm_bkt, A, N_WM);
    mfma_gemm<0><<<gW, blk, 0, stream>>>(A, nullptr, nullptr, wm_W2, wm_b2, Cc,
                                         N_WM, Gd, Gd, 1);
    // ===== tmp (K-slot gather-sum) =====
    tmp_kernel<<<N_F / 4, blk, 0, stream>>>(Cc, extra, t2np, D);
    // ===== fc1: E = concat(tmp, text) @ fc1_W + b =====
    mfma_gemm<2><<<gF, blk, 0, stream>>>(D, text, nullptr, fc1_W, fc1_b, Ee,
                                         N_F, Gd, Gd + PLM, 0);
    // ===== FSTM gather =====
    gather_kernel<<<N_F / 4, blk, 0, stream>>>(Ee, f_ids, F);
    // ===== FSTM layer 1 =====
    aggregate_kernel<<<N_F / 4, blk, 0, stream>>>(F, fs_off, fs_bkt, A, N_F);
    mfma_gemm<0><<<gF, blk, 0, stream>>>(A, nullptr, nullptr, fs_W1, fs_b1, H,
                                         N_F, Gd, Gd, 1);
    // ===== FSTM layer 2 =====
    aggregate_kernel<<<N_F / 4, blk, 0, stream>>>(H, fs_off, fs_bkt, A, N_F);
    mfma_gemm<0><<<gF, blk, 0, stream>>>(A, nullptr, nullptr, fs_W2, fs_b2, T,
                                         N_F, Gd, Gd, 1);
    // ===== fc3: out = concat(text, tmp, temporal) @ fc3_W + b =====
    mfma_gemm<3><<<gO, blk, 0, stream>>>(text, D, T, fc3_W, fc3_b, out,
                                         N_F, PLM, PLM + 2 * Gd, 0);
}

// Round 4
// 894.272 us; speedup vs baseline: 7.6158x; 1.2854x over previous
//
#include <hip/hip_runtime.h>

// Problem constants (match reference)
#define Bsz 8
#define Ssz 2048
#define PLM 768
#define Gd  256
#define N_WM 50000
#define E_WM 800000
#define N_F  16384   // B*S
#define E_F  131072
#define Kc   4

typedef unsigned short ushort_t;
typedef short short8 __attribute__((ext_vector_type(8)));
typedef float f32x4 __attribute__((ext_vector_type(4)));

// RNE float -> bf16 bits
__device__ __forceinline__ ushort_t f2bf(float f) {
    union { float f; unsigned int u; } v; v.f = f;
    unsigned int r = (v.u + 0x7fffu + ((v.u >> 16) & 1u)) >> 16;
    return (ushort_t)r;
}
__device__ __forceinline__ float bf2f(ushort_t b) {
    union { unsigned int u; float f; } v; v.u = ((unsigned int)b) << 16;
    return v.f;
}
__device__ __forceinline__ float4 bf4f(ushort4 u) {
    return make_float4(bf2f(u.x), bf2f(u.y), bf2f(u.z), bf2f(u.w));
}

// async global->LDS, 16B per lane; LDS dest must be wave-uniform base
__device__ __forceinline__ void gl2lds16(const ushort_t* g, ushort_t* l) {
    __builtin_amdgcn_global_load_lds(
        (const __attribute__((address_space(1))) unsigned int*)g,
        (__attribute__((address_space(3))) unsigned int*)l, 16, 0, 0);
}

// ---------------------------------------------------------------------------
// fp32 -> bf16 bulk convert (n4 = n/4 float4s)
// ---------------------------------------------------------------------------
__global__ void cvt_bf_kernel(const float* __restrict__ in,
                              ushort_t* __restrict__ out, int n4) {
    int i = blockIdx.x * 256 + threadIdx.x;
    if (i < n4) {
        float4 v = ((const float4*)in)[i];
        ushort4 u;
        u.x = f2bf(v.x); u.y = f2bf(v.y); u.z = f2bf(v.z); u.w = f2bf(v.w);
        ((ushort4*)out)[i] = u;
    }
}

// W[k][n] fp32 -> Wt[n][k] bf16
__global__ void wt_kernel(const float* __restrict__ W, ushort_t* __restrict__ Wt,
                          int K, int N) {
    int idx = blockIdx.x * 256 + threadIdx.x;
    if (idx < N * K) {
        int n = idx / K, k = idx % K;
        Wt[idx] = f2bf(W[(size_t)k * N + n]);
    }
}

// ---------------------------------------------------------------------------
// CSR build: histogram -> exclusive scan -> bucket fill (int atomics only)
// ---------------------------------------------------------------------------
__global__ void hist_kernel(const int* __restrict__ dst, int* __restrict__ cnt, int E) {
    int e = blockIdx.x * 256 + threadIdx.x;
    if (e < E) atomicAdd(&cnt[dst[e]], 1);
}

__global__ __launch_bounds__(256) void scan_kernel(int* __restrict__ cnt,
                                                   int* __restrict__ off, int n) {
    __shared__ int base[257];
    int t = threadIdx.x;
    int chunk = (n + 255) / 256;
    int lo = t * chunk;
    int hi = lo + chunk; if (hi > n) hi = n; if (lo > n) lo = n;
    int s = 0;
    for (int i = lo; i < hi; ++i) s += cnt[i];
    base[t + 1] = s;
    __syncthreads();
    if (t == 0) {
        base[0] = 0;
        for (int j = 1; j <= 256; ++j) base[j] += base[j - 1];
    }
    __syncthreads();
    int acc = base[t];
    for (int i = lo; i < hi; ++i) {
        int c = cnt[i];
        off[i] = acc;
        cnt[i] = acc;   // cursor
        acc += c;
    }
    if (t == 255) off[n] = base[256];
}

__global__ void fill_kernel(const int* __restrict__ src, const int* __restrict__ dst,
                            int* __restrict__ cur, int* __restrict__ bucket, int E) {
    int e = blockIdx.x * 256 + threadIdx.x;
    if (e < E) {
        int p = atomicAdd(&cur[dst[e]], 1);
        bucket[p] = src[e];
    }
}

// ---------------------------------------------------------------------------
// aggregate (bf16): hm[i] = h[i] + sum_{j in CSR(i)} h[bucket[j]]
// one wave per node, ushort4 (8B) per lane, fp32 accumulate
// ---------------------------------------------------------------------------
__global__ void aggregate_kernel(const ushort_t* __restrict__ h,
                                 const int* __restrict__ off,
                                 const int* __restrict__ bucket,
                                 ushort_t* __restrict__ hm, int n) {
    int i = blockIdx.x * 4 + (threadIdx.x >> 6);
    if (i >= n) return;
    int lane = threadIdx.x & 63;
    int s0 = off[i], s1 = off[i + 1];
    const ushort4* hp = (const ushort4*)h;   // 64 ushort4 per row
    float4 acc = bf4f(hp[(size_t)i * 64 + lane]);
    for (int j = s0; j < s1; ++j) {
        int s = bucket[j];
        float4 v = bf4f(hp[(size_t)s * 64 + lane]);
        acc.x += v.x; acc.y += v.y; acc.z += v.z; acc.w += v.w;
    }
    ushort4 u;
    u.x = f2bf(acc.x); u.y = f2bf(acc.y); u.z = f2bf(acc.z); u.w = f2bf(acc.w);
    ((ushort4*)hm)[(size_t)i * 64 + lane] = u;
}

// ---------------------------------------------------------------------------
// tmp[i] = sum_k table[token2nodepos[i,k]+2]   (bf16 table, fp32 accumulate)
// ---------------------------------------------------------------------------
__global__ void tmp_kernel(const ushort_t* __restrict__ gemb,
                           const ushort_t* __restrict__ extra,
                           const int* __restrict__ t2np,
                           ushort_t* __restrict__ D) {
    int i = blockIdx.x * 4 + (threadIdx.x >> 6);
    int lane = threadIdx.x & 63;
    float4 s = make_float4(0.f, 0.f, 0.f, 0.f);
#pragma unroll
    for (int k = 0; k < Kc; ++k) {
        int idx = t2np[i * Kc + k] + 2;
        const ushort4* row = (idx < 2) ? (const ushort4*)(extra + (size_t)idx * Gd)
                                       : (const ushort4*)(gemb + (size_t)(idx - 2) * Gd);
        float4 v = bf4f(row[lane]);
        s.x += v.x; s.y += v.y; s.z += v.z; s.w += v.w;
    }
    ushort4 u;
    u.x = f2bf(s.x); u.y = f2bf(s.y); u.z = f2bf(s.z); u.w = f2bf(s.w);
    ((ushort4*)D)[(size_t)i * 64 + lane] = u;
}

// ---------------------------------------------------------------------------
// row gather (bf16): F[i] = E[ids[i]]
// ---------------------------------------------------------------------------
__global__ void gather_kernel(const ushort_t* __restrict__ Ein,
                              const int* __restrict__ ids,
                              ushort_t* __restrict__ F) {
    int i = blockIdx.x * 4 + (threadIdx.x >> 6);
    int lane = threadIdx.x & 63;
    ((ushort4*)F)[(size_t)i * 64 + lane] =
        ((const ushort4*)Ein)[(size_t)ids[i] * 64 + lane];
}

// ---------------------------------------------------------------------------
// bf16 MFMA GEMM, m97 structure: 128x128 tile, BK=64, global_load_lds width 16
// A operand bf16 (row-major in k), B = pre-transposed bf16 Wt[n][k].
// MODE 0: A = p0[row][k], rowlen K
// MODE 2: A = k<256 ? p0[row][k] : p1(row, k-256) rowlen 768     (tmp|text), K=1024
// MODE 3: A = k<768 ? p0 : k<1024 ? p1 : p2                      (text|tmp|temporal), K=1280
// OUTBF: 1 -> bf16 C, 0 -> fp32 C
// ---------------------------------------------------------------------------
#define TBM 128
#define TBN 128
#define TBK 64

template <int MODE, int OUTBF>
__global__ __launch_bounds__(256) void mfma_gemm(
    const ushort_t* __restrict__ p0, const ushort_t* __restrict__ p1,
    const ushort_t* __restrict__ p2, const ushort_t* __restrict__ Wt,
    const float* __restrict__ bias, void* __restrict__ Cv,
    int M, int N, int K, int relu) {
    __shared__ ushort_t As[TBM * TBK];   // [row][k], stride 64, no pad (lds-dma)
    __shared__ ushort_t Bs[TBN * TBK];   // [col][k]

    int tid  = threadIdx.x;
    int lane = tid & 63;
    int wave = tid >> 6;
    int wm = (wave >> 1) * 64, wn = (wave & 1) * 64;
    int row0 = blockIdx.y * TBM, col0 = blockIdx.x * TBN;
    int l15 = lane & 15, l4 = lane >> 4;

    f32x4 acc[4][4];
#pragma unroll
    for (int i = 0; i < 4; ++i)
#pragma unroll
        for (int j = 0; j < 4; ++j)
            acc[i][j] = (f32x4){0.f, 0.f, 0.f, 0.f};

    for (int k0 = 0; k0 < K; k0 += TBK) {
        // ---- stage A via lds-dma: 16KB, 4 iters x (4 waves x 1KB) ----
#pragma unroll
        for (int it = 0; it < 4; ++it) {
            int eb = it * 2048 + wave * 512;   // wave-uniform elem base
            int le = eb + lane * 8;
            int r  = le >> 6;
            int kl = le & 63;
            int grow = row0 + r; if (grow > M - 1) grow = M - 1;
            int gk = k0 + kl;
            const ushort_t* gp;
            if (MODE == 0)
                gp = p0 + (size_t)grow * K + gk;
            else if (MODE == 2)
                gp = (gk < 256) ? p0 + (size_t)grow * 256 + gk
                                : p1 + (size_t)grow * 768 + (gk - 256);
            else
                gp = (gk < 768) ? p0 + (size_t)grow * 768 + gk
                   : (gk < 1024) ? p1 + (size_t)grow * 256 + (gk - 768)
                                 : p2 + (size_t)grow * 256 + (gk - 1024);
            gl2lds16(gp, &As[eb]);
        }
        // ---- stage B via lds-dma ----
#pragma unroll
        for (int it = 0; it < 4; ++it) {
            int eb = it * 2048 + wave * 512;
            int le = eb + lane * 8;
            int nl = le >> 6;
            int kl = le & 63;
            const ushort_t* gp = Wt + (size_t)(col0 + nl) * K + k0 + kl;
            gl2lds16(gp, &Bs[eb]);
        }
        __syncthreads();

#pragma unroll
        for (int ks = 0; ks < TBK; ks += 32) {
            short8 af[4], bfr[4];
#pragma unroll
            for (int mi = 0; mi < 4; ++mi)
                af[mi] = *(const short8*)&As[(wm + mi * 16 + l15) * TBK + ks + l4 * 8];
#pragma unroll
            for (int ni = 0; ni < 4; ++ni)
                bfr[ni] = *(const short8*)&Bs[(wn + ni * 16 + l15) * TBK + ks + l4 * 8];
#pragma unroll
            for (int mi = 0; mi < 4; ++mi)
#pragma unroll
                for (int ni = 0; ni < 4; ++ni)
                    acc[mi][ni] = __builtin_amdgcn_mfma_f32_16x16x32_bf16(
                        af[mi], bfr[ni], acc[mi][ni], 0, 0, 0);
        }
        __syncthreads();
    }

    // ---- epilogue: bias (+relu); C/D layout col=lane&15, row=(lane>>4)*4+reg ----
#pragma unroll
    for (int ni = 0; ni < 4; ++ni) {
        int c = col0 + wn + ni * 16 + l15;
        float bv = bias[c];
#pragma unroll
        for (int mi = 0; mi < 4; ++mi) {
#pragma unroll
            for (int r = 0; r < 4; ++r) {
                int rr = row0 + wm + mi * 16 + l4 * 4 + r;
                if (rr < M) {
                    float v = acc[mi][ni][r] + bv;
                    if (relu) v = fmaxf(v, 0.f);
                    if (OUTBF) ((ushort_t*)Cv)[(size_t)rr * N + c] = f2bf(v);
                    else       ((float*)Cv)[(size_t)rr * N + c] = v;
                }
            }
        }
    }
}

// ---------------------------------------------------------------------------
extern "C" void kernel_launch(void* const* d_in, const int* in_sizes, int n_in,
                              void* d_out, int out_size, void* d_ws, size_t ws_size,
                              hipStream_t stream) {
    const float* text    = (const float*)d_in[0];   // [16384, 768]
    const float* wm_x    = (const float*)d_in[1];   // [50000, 256]
    const int*   wm_ei   = (const int*)d_in[2];     // [2, 800000]
    const int*   t2np    = (const int*)d_in[3];     // [16384, 4]
    const int*   f_ids   = (const int*)d_in[4];     // [16384]
    const int*   f_ei    = (const int*)d_in[5];     // [2, 131072]
    const float* extra   = (const float*)d_in[6];   // [2, 256]
    const float* wm_W1   = (const float*)d_in[7];
    const float* wm_b1   = (const float*)d_in[8];
    const float* wm_W2   = (const float*)d_in[9];
    const float* wm_b2   = (const float*)d_in[10];
    const float* fs_W1   = (const float*)d_in[11];
    const float* fs_b1   = (const float*)d_in[12];
    const float* fs_W2   = (const float*)d_in[13];
    const float* fs_b2   = (const float*)d_in[14];
    const float* fc1_W   = (const float*)d_in[15];  // [1024, 256]
    const float* fc1_b   = (const float*)d_in[16];
    const float* fc3_W   = (const float*)d_in[17];  // [1280, 768]
    const float* fc3_b   = (const float*)d_in[18];
    float* out = (float*)d_out;                     // [16384, 768]

    // ---- workspace layout (bf16 = ushort) ----
    ushort_t* Xb  = (ushort_t*)d_ws;            // [50000*256] wm_x bf16 (reused: h1)
    ushort_t* Ag  = Xb + 12800000;              // [50000*256] aggregate out
    ushort_t* Gm  = Ag + 12800000;              // [50000*256] gemb (reused: F, H)
    ushort_t* Tx  = Gm + 12800000;              // [16384*768] text bf16
    ushort_t* Dt  = Tx + 12582912;              // [16384*256] tmp
    ushort_t* Ee  = Dt + 4194304;               // [16384*256] gte (reused: T)
    ushort_t* Wv  = Ee + 4194304;               // weights, transposed bf16
    ushort_t* wt_wm1 = Wv;                      //  65536
    ushort_t* wt_wm2 = wt_wm1 + 65536;          //  65536
    ushort_t* wt_fs1 = wt_wm2 + 65536;          //  65536
    ushort_t* wt_fs2 = wt_fs1 + 65536;          //  65536
    ushort_t* wt_fc1 = wt_fs2 + 65536;          //  262144
    ushort_t* wt_fc3 = wt_fc1 + 262144;         //  983040
    ushort_t* Exb    = wt_fc3 + 983040;         //  512
    int* wm_off = (int*)(Exb + 512);            // [N_WM+1]
    int* wm_cnt = wm_off + N_WM + 1;
    int* wm_bkt = wm_cnt + N_WM;                // [E_WM]
    int* fs_off = wm_bkt + E_WM;                // [N_F+1]
    int* fs_cnt = fs_off + N_F + 1;
    int* fs_bkt = fs_cnt + N_F;                 // [E_F]

    ushort_t* h1 = Xb;                 // gemm1 out overwrites Xb (dead)
    ushort_t* F  = Gm;                 // gather out overwrites gemb (dead)
    ushort_t* H  = Gm + 4194304;
    ushort_t* T  = Ee;                 // fstm out overwrites Ee (dead)

    const int* wm_src = wm_ei;
    const int* wm_dst = wm_ei + E_WM;
    const int* f_src  = f_ei;
    const int* f_dst  = f_ei + E_F;

    dim3 blk(256);
    dim3 gW(Gd / TBN, (N_WM + TBM - 1) / TBM);   // 2 x 391
    dim3 gF(Gd / TBN, N_F / TBM);                // 2 x 128
    dim3 gO(PLM / TBN, N_F / TBM);               // 6 x 128

    // ===== CSR build =====
    hipMemsetAsync(wm_cnt, 0, N_WM * sizeof(int), stream);
    hipMemsetAsync(fs_cnt, 0, N_F * sizeof(int), stream);
    hist_kernel<<<(E_WM + 255) / 256, blk, 0, stream>>>(wm_dst, wm_cnt, E_WM);
    hist_kernel<<<(E_F + 255) / 256, blk, 0, stream>>>(f_dst, fs_cnt, E_F);
    scan_kernel<<<1, blk, 0, stream>>>(wm_cnt, wm_off, N_WM);
    scan_kernel<<<1, blk, 0, stream>>>(fs_cnt, fs_off, N_F);
    fill_kernel<<<(E_WM + 255) / 256, blk, 0, stream>>>(wm_src, wm_dst, wm_cnt, wm_bkt, E_WM);
    fill_kernel<<<(E_F + 255) / 256, blk, 0, stream>>>(f_src, f_dst, fs_cnt, fs_bkt, E_F);

    // ===== one-time conversions =====
    cvt_bf_kernel<<<(3200000 + 255) / 256, blk, 0, stream>>>(wm_x, Xb, 3200000);
    cvt_bf_kernel<<<(3145728 + 255) / 256, blk, 0, stream>>>(text, Tx, 3145728);
    cvt_bf_kernel<<<1, blk, 0, stream>>>(extra, Exb, 128);
    wt_kernel<<<(65536 + 255) / 256, blk, 0, stream>>>(wm_W1, wt_wm1, 256, 256);
    wt_kernel<<<(65536 + 255) / 256, blk, 0, stream>>>(wm_W2, wt_wm2, 256, 256);
    wt_kernel<<<(65536 + 255) / 256, blk, 0, stream>>>(fs_W1, wt_fs1, 256, 256);
    wt_kernel<<<(65536 + 255) / 256, blk, 0, stream>>>(fs_W2, wt_fs2, 256, 256);
    wt_kernel<<<(262144 + 255) / 256, blk, 0, stream>>>(fc1_W, wt_fc1, 1024, 256);
    wt_kernel<<<(983040 + 255) / 256, blk, 0, stream>>>(fc3_W, wt_fc3, 1280, 768);

    // ===== WM layer 1 =====
    aggregate_kernel<<<(N_WM + 3) / 4, blk, 0, stream>>>(Xb, wm_off, wm_bkt, Ag, N_WM);
    mfma_gemm<0, 1><<<gW, blk, 0, stream>>>(Ag, nullptr, nullptr, wt_wm1, wm_b1,
                                            h1, N_WM, Gd, Gd, 1);
    // ===== WM layer 2 =====
    aggregate_kernel<<<(N_WM + 3) / 4, blk, 0, stream>>>(h1, wm_off, wm_bkt, Ag, N_WM);
    mfma_gemm<0, 1><<<gW, blk, 0, stream>>>(Ag, nullptr, nullptr, wt_wm2, wm_b2,
                                            Gm, N_WM, Gd, Gd, 1);
    // ===== tmp =====
    tmp_kernel<<<N_F / 4, blk, 0, stream>>>(Gm, Exb, t2np, Dt);
    // ===== fc1: Ee = concat(tmp, text) @ fc1_W + b =====
    mfma_gemm<2, 1><<<gF, blk, 0, stream>>>(Dt, Tx, nullptr, wt_fc1, fc1_b,
                                            Ee, N_F, Gd, Gd + PLM, 0);
    // ===== FSTM gather =====
    gather_kernel<<<N_F / 4, blk, 0, stream>>>(Ee, f_ids, F);
    // ===== FSTM layer 1 =====
    aggregate_kernel<<<N_F / 4, blk, 0, stream>>>(F, fs_off, fs_bkt, Ag, N_F);
    mfma_gemm<0, 1><<<gF, blk, 0, stream>>>(Ag, nullptr, nullptr, wt_fs1, fs_b1,
                                            H, N_F, Gd, Gd, 1);
    // ===== FSTM layer 2 =====
    aggregate_kernel<<<N_F / 4, blk, 0, stream>>>(H, fs_off, fs_bkt, Ag, N_F);
    mfma_gemm<0, 1><<<gF, blk, 0, stream>>>(Ag, nullptr, nullptr, wt_fs2, fs_b2,
                                            T, N_F, Gd, Gd, 1);
    // ===== fc3: out = concat(text, tmp, temporal) @ fc3_W + b (fp32 out) =====
    mfma_gemm<3, 0><<<gO, blk, 0, stream>>>(Tx, Dt, T, wt_fc3, fc3_b,
                                            out, N_F, PLM, PLM + 2 * Gd, 0);
}

// Round 5
// 751.046 us; speedup vs baseline: 9.0682x; 1.1907x over previous
//
#include <hip/hip_runtime.h>

// Problem constants (match reference)
#define Bsz 8
#define Ssz 2048
#define PLM 768
#define Gd  256
#define N_WM 50000
#define E_WM 800000
#define N_F  16384   // B*S
#define E_F  131072
#define Kc   4

typedef unsigned short ushort_t;
typedef short short8 __attribute__((ext_vector_type(8)));
typedef float f32x4 __attribute__((ext_vector_type(4)));

// RNE float -> bf16 bits
__device__ __forceinline__ ushort_t f2bf(float f) {
    union { float f; unsigned int u; } v; v.f = f;
    unsigned int r = (v.u + 0x7fffu + ((v.u >> 16) & 1u)) >> 16;
    return (ushort_t)r;
}
__device__ __forceinline__ float bf2f(ushort_t b) {
    union { unsigned int u; float f; } v; v.u = ((unsigned int)b) << 16;
    return v.f;
}
__device__ __forceinline__ float4 bf4f(ushort4 u) {
    return make_float4(bf2f(u.x), bf2f(u.y), bf2f(u.z), bf2f(u.w));
}

// async global->LDS, 16B per lane; LDS dest must be wave-uniform base
__device__ __forceinline__ void gl2lds16(const ushort_t* g, ushort_t* l) {
    __builtin_amdgcn_global_load_lds(
        (const __attribute__((address_space(1))) unsigned int*)g,
        (__attribute__((address_space(3))) unsigned int*)l, 16, 0, 0);
}

// ---------------------------------------------------------------------------
// fp32 -> bf16 bulk convert (n4 = n/4 float4s)
// ---------------------------------------------------------------------------
__global__ void cvt_bf_kernel(const float* __restrict__ in,
                              ushort_t* __restrict__ out, int n4) {
    int i = blockIdx.x * 256 + threadIdx.x;
    if (i < n4) {
        float4 v = ((const float4*)in)[i];
        ushort4 u;
        u.x = f2bf(v.x); u.y = f2bf(v.y); u.z = f2bf(v.z); u.w = f2bf(v.w);
        ((ushort4*)out)[i] = u;
    }
}

// W[k][n] fp32 -> Wt[n][k] bf16
__global__ void wt_kernel(const float* __restrict__ W, ushort_t* __restrict__ Wt,
                          int K, int N) {
    int idx = blockIdx.x * 256 + threadIdx.x;
    if (idx < N * K) {
        int n = idx / K, k = idx % K;
        Wt[idx] = f2bf(W[(size_t)k * N + n]);
    }
}

// ---------------------------------------------------------------------------
// CSR build: histogram -> 3-phase parallel exclusive scan -> bucket fill
// ---------------------------------------------------------------------------
__global__ void hist_kernel(const int* __restrict__ dst, int* __restrict__ cnt, int E) {
    int e = blockIdx.x * 256 + threadIdx.x;
    if (e < E) atomicAdd(&cnt[dst[e]], 1);
}

// phase 1: per-block (1024 elems) sum -> bsum[b]
__global__ __launch_bounds__(256) void scan_part1(const int* __restrict__ cnt,
                                                  int* __restrict__ bsum, int n) {
    __shared__ int sm[256];
    int t = threadIdx.x;
    int base = blockIdx.x * 1024 + t * 4;
    int s = 0;
    if (base + 3 < n) {
        int4 q = *(const int4*)&cnt[base];
        s = q.x + q.y + q.z + q.w;
    } else {
#pragma unroll
        for (int i = 0; i < 4; ++i) if (base + i < n) s += cnt[base + i];
    }
    sm[t] = s; __syncthreads();
#pragma unroll
    for (int st = 128; st > 0; st >>= 1) {
        if (t < st) sm[t] += sm[t + st];
        __syncthreads();
    }
    if (t == 0) bsum[blockIdx.x] = sm[0];
}

// phase 2: exclusive scan of block sums (nb <= 64, trivial)
__global__ void scan_bsums(int* __restrict__ bsum, int nb) {
    if (threadIdx.x == 0 && blockIdx.x == 0) {
        int acc = 0;
        for (int i = 0; i < nb; ++i) { int c = bsum[i]; bsum[i] = acc; acc += c; }
    }
}

// phase 3: in-block scan + add block base; write off[] and cursor (cnt[])
__global__ __launch_bounds__(256) void scan_part2(int* __restrict__ cnt,
                                                  int* __restrict__ off,
                                                  const int* __restrict__ bsum,
                                                  int n, int total) {
    __shared__ int sm[256];
    int t = threadIdx.x;
    int base = blockIdx.x * 1024 + t * 4;
    int v0 = 0, v1 = 0, v2 = 0, v3 = 0;
    if (base + 3 < n) {
        int4 q = *(const int4*)&cnt[base];
        v0 = q.x; v1 = q.y; v2 = q.z; v3 = q.w;
    } else {
        if (base + 0 < n) v0 = cnt[base + 0];
        if (base + 1 < n) v1 = cnt[base + 1];
        if (base + 2 < n) v2 = cnt[base + 2];
        if (base + 3 < n) v3 = cnt[base + 3];
    }
    int s = v0 + v1 + v2 + v3;
    sm[t] = s;
    __syncthreads();
#pragma unroll
    for (int st = 1; st < 256; st <<= 1) {
        int x = (t >= st) ? sm[t - st] : 0;
        __syncthreads();
        sm[t] += x;
        __syncthreads();
    }
    int ex = bsum[blockIdx.x] + sm[t] - s;   // exclusive prefix of this thread
    int o0 = ex, o1 = ex + v0, o2 = o1 + v1, o3 = o2 + v2;
    if (base + 0 < n) { off[base + 0] = o0; cnt[base + 0] = o0; }
    if (base + 1 < n) { off[base + 1] = o1; cnt[base + 1] = o1; }
    if (base + 2 < n) { off[base + 2] = o2; cnt[base + 2] = o2; }
    if (base + 3 < n) { off[base + 3] = o3; cnt[base + 3] = o3; }
    if (blockIdx.x == 0 && t == 0) off[n] = total;
}

__global__ void fill_kernel(const int* __restrict__ src, const int* __restrict__ dst,
                            int* __restrict__ cur, int* __restrict__ bucket, int E) {
    int e = blockIdx.x * 256 + threadIdx.x;
    if (e < E) {
        int p = atomicAdd(&cur[dst[e]], 1);
        bucket[p] = src[e];
    }
}

// ---------------------------------------------------------------------------
// aggregate (bf16): hm[i] = h[i] + sum_{j in CSR(i)} h[bucket[j]]
// one wave per node, ushort4 (8B) per lane, fp32 accumulate
// ---------------------------------------------------------------------------
__global__ void aggregate_kernel(const ushort_t* __restrict__ h,
                                 const int* __restrict__ off,
                                 const int* __restrict__ bucket,
                                 ushort_t* __restrict__ hm, int n) {
    int i = blockIdx.x * 4 + (threadIdx.x >> 6);
    if (i >= n) return;
    int lane = threadIdx.x & 63;
    int s0 = off[i], s1 = off[i + 1];
    const ushort4* hp = (const ushort4*)h;   // 64 ushort4 per row
    float4 acc = bf4f(hp[(size_t)i * 64 + lane]);
    for (int j = s0; j < s1; ++j) {
        int s = bucket[j];
        float4 v = bf4f(hp[(size_t)s * 64 + lane]);
        acc.x += v.x; acc.y += v.y; acc.z += v.z; acc.w += v.w;
    }
    ushort4 u;
    u.x = f2bf(acc.x); u.y = f2bf(acc.y); u.z = f2bf(acc.z); u.w = f2bf(acc.w);
    ((ushort4*)hm)[(size_t)i * 64 + lane] = u;
}

// ---------------------------------------------------------------------------
// tmp[i] = sum_k table[token2nodepos[i,k]+2]   (bf16 table, fp32 accumulate)
// ---------------------------------------------------------------------------
__global__ void tmp_kernel(const ushort_t* __restrict__ gemb,
                           const ushort_t* __restrict__ extra,
                           const int* __restrict__ t2np,
                           ushort_t* __restrict__ D) {
    int i = blockIdx.x * 4 + (threadIdx.x >> 6);
    int lane = threadIdx.x & 63;
    float4 s = make_float4(0.f, 0.f, 0.f, 0.f);
#pragma unroll
    for (int k = 0; k < Kc; ++k) {
        int idx = t2np[i * Kc + k] + 2;
        const ushort4* row = (idx < 2) ? (const ushort4*)(extra + (size_t)idx * Gd)
                                       : (const ushort4*)(gemb + (size_t)(idx - 2) * Gd);
        float4 v = bf4f(row[lane]);
        s.x += v.x; s.y += v.y; s.z += v.z; s.w += v.w;
    }
    ushort4 u;
    u.x = f2bf(s.x); u.y = f2bf(s.y); u.z = f2bf(s.z); u.w = f2bf(s.w);
    ((ushort4*)D)[(size_t)i * 64 + lane] = u;
}

// ---------------------------------------------------------------------------
// row gather (bf16): F[i] = E[ids[i]]
// ---------------------------------------------------------------------------
__global__ void gather_kernel(const ushort_t* __restrict__ Ein,
                              const int* __restrict__ ids,
                              ushort_t* __restrict__ F) {
    int i = blockIdx.x * 4 + (threadIdx.x >> 6);
    int lane = threadIdx.x & 63;
    ((ushort4*)F)[(size_t)i * 64 + lane] =
        ((const ushort4*)Ein)[(size_t)ids[i] * 64 + lane];
}

// ---------------------------------------------------------------------------
// bf16 MFMA GEMM, m97 structure: 128x128 tile, BK=64, global_load_lds width 16
// A operand bf16 (row-major in k), B = pre-transposed bf16 Wt[n][k].
// MODE 0: A = p0[row][k], rowlen K
// MODE 2: A = k<256 ? p0[row][k] : p1(row, k-256) rowlen 768     (tmp|text), K=1024
// MODE 3: A = k<768 ? p0 : k<1024 ? p1 : p2                      (text|tmp|temporal), K=1280
// OUTBF: 1 -> bf16 C, 0 -> fp32 C
// ---------------------------------------------------------------------------
#define TBM 128
#define TBN 128
#define TBK 64

template <int MODE, int OUTBF>
__global__ __launch_bounds__(256) void mfma_gemm(
    const ushort_t* __restrict__ p0, const ushort_t* __restrict__ p1,
    const ushort_t* __restrict__ p2, const ushort_t* __restrict__ Wt,
    const float* __restrict__ bias, void* __restrict__ Cv,
    int M, int N, int K, int relu) {
    __shared__ ushort_t As[TBM * TBK];   // [row][k], stride 64, no pad (lds-dma)
    __shared__ ushort_t Bs[TBN * TBK];   // [col][k]

    int tid  = threadIdx.x;
    int lane = tid & 63;
    int wave = tid >> 6;
    int wm = (wave >> 1) * 64, wn = (wave & 1) * 64;
    int row0 = blockIdx.y * TBM, col0 = blockIdx.x * TBN;
    int l15 = lane & 15, l4 = lane >> 4;

    f32x4 acc[4][4];
#pragma unroll
    for (int i = 0; i < 4; ++i)
#pragma unroll
        for (int j = 0; j < 4; ++j)
            acc[i][j] = (f32x4){0.f, 0.f, 0.f, 0.f};

    for (int k0 = 0; k0 < K; k0 += TBK) {
        // ---- stage A via lds-dma: 16KB, 4 iters x (4 waves x 1KB) ----
#pragma unroll
        for (int it = 0; it < 4; ++it) {
            int eb = it * 2048 + wave * 512;   // wave-uniform elem base
            int le = eb + lane * 8;
            int r  = le >> 6;
            int kl = le & 63;
            int grow = row0 + r; if (grow > M - 1) grow = M - 1;
            int gk = k0 + kl;
            const ushort_t* gp;
            if (MODE == 0)
                gp = p0 + (size_t)grow * K + gk;
            else if (MODE == 2)
                gp = (gk < 256) ? p0 + (size_t)grow * 256 + gk
                                : p1 + (size_t)grow * 768 + (gk - 256);
            else
                gp = (gk < 768) ? p0 + (size_t)grow * 768 + gk
                   : (gk < 1024) ? p1 + (size_t)grow * 256 + (gk - 768)
                                 : p2 + (size_t)grow * 256 + (gk - 1024);
            gl2lds16(gp, &As[eb]);
        }
        // ---- stage B via lds-dma ----
#pragma unroll
        for (int it = 0; it < 4; ++it) {
            int eb = it * 2048 + wave * 512;
            int le = eb + lane * 8;
            int nl = le >> 6;
            int kl = le & 63;
            const ushort_t* gp = Wt + (size_t)(col0 + nl) * K + k0 + kl;
            gl2lds16(gp, &Bs[eb]);
        }
        __syncthreads();

#pragma unroll
        for (int ks = 0; ks < TBK; ks += 32) {
            short8 af[4], bfr[4];
#pragma unroll
            for (int mi = 0; mi < 4; ++mi)
                af[mi] = *(const short8*)&As[(wm + mi * 16 + l15) * TBK + ks + l4 * 8];
#pragma unroll
            for (int ni = 0; ni < 4; ++ni)
                bfr[ni] = *(const short8*)&Bs[(wn + ni * 16 + l15) * TBK + ks + l4 * 8];
#pragma unroll
            for (int mi = 0; mi < 4; ++mi)
#pragma unroll
                for (int ni = 0; ni < 4; ++ni)
                    acc[mi][ni] = __builtin_amdgcn_mfma_f32_16x16x32_bf16(
                        af[mi], bfr[ni], acc[mi][ni], 0, 0, 0);
        }
        __syncthreads();
    }

    // ---- epilogue: bias (+relu); C/D layout col=lane&15, row=(lane>>4)*4+reg ----
#pragma unroll
    for (int ni = 0; ni < 4; ++ni) {
        int c = col0 + wn + ni * 16 + l15;
        float bv = bias[c];
#pragma unroll
        for (int mi = 0; mi < 4; ++mi) {
#pragma unroll
            for (int r = 0; r < 4; ++r) {
                int rr = row0 + wm + mi * 16 + l4 * 4 + r;
                if (rr < M) {
                    float v = acc[mi][ni][r] + bv;
                    if (relu) v = fmaxf(v, 0.f);
                    if (OUTBF) ((ushort_t*)Cv)[(size_t)rr * N + c] = f2bf(v);
                    else       ((float*)Cv)[(size_t)rr * N + c] = v;
                }
            }
        }
    }
}

// ---------------------------------------------------------------------------
extern "C" void kernel_launch(void* const* d_in, const int* in_sizes, int n_in,
                              void* d_out, int out_size, void* d_ws, size_t ws_size,
                              hipStream_t stream) {
    const float* text    = (const float*)d_in[0];   // [16384, 768]
    const float* wm_x    = (const float*)d_in[1];   // [50000, 256]
    const int*   wm_ei   = (const int*)d_in[2];     // [2, 800000]
    const int*   t2np    = (const int*)d_in[3];     // [16384, 4]
    const int*   f_ids   = (const int*)d_in[4];     // [16384]
    const int*   f_ei    = (const int*)d_in[5];     // [2, 131072]
    const float* extra   = (const float*)d_in[6];   // [2, 256]
    const float* wm_W1   = (const float*)d_in[7];
    const float* wm_b1   = (const float*)d_in[8];
    const float* wm_W2   = (const float*)d_in[9];
    const float* wm_b2   = (const float*)d_in[10];
    const float* fs_W1   = (const float*)d_in[11];
    const float* fs_b1   = (const float*)d_in[12];
    const float* fs_W2   = (const float*)d_in[13];
    const float* fs_b2   = (const float*)d_in[14];
    const float* fc1_W   = (const float*)d_in[15];  // [1024, 256]
    const float* fc1_b   = (const float*)d_in[16];
    const float* fc3_W   = (const float*)d_in[17];  // [1280, 768]
    const float* fc3_b   = (const float*)d_in[18];
    float* out = (float*)d_out;                     // [16384, 768]

    // ---- workspace layout (bf16 = ushort) ----
    ushort_t* Xb  = (ushort_t*)d_ws;            // [50000*256] wm_x bf16 (reused: h1)
    ushort_t* Ag  = Xb + 12800000;              // [50000*256] aggregate out
    ushort_t* Gm  = Ag + 12800000;              // [50000*256] gemb (reused: F, H)
    ushort_t* Tx  = Gm + 12800000;              // [16384*768] text bf16
    ushort_t* Dt  = Tx + 12582912;              // [16384*256] tmp
    ushort_t* Ee  = Dt + 4194304;               // [16384*256] gte (reused: T)
    ushort_t* Wv  = Ee + 4194304;               // weights, transposed bf16
    ushort_t* wt_wm1 = Wv;                      //  65536
    ushort_t* wt_wm2 = wt_wm1 + 65536;          //  65536
    ushort_t* wt_fs1 = wt_wm2 + 65536;          //  65536
    ushort_t* wt_fs2 = wt_fs1 + 65536;          //  65536
    ushort_t* wt_fc1 = wt_fs2 + 65536;          //  262144
    ushort_t* wt_fc3 = wt_fc1 + 262144;         //  983040
    ushort_t* Exb    = wt_fc3 + 983040;         //  512
    int* wm_off = (int*)(Exb + 512);            // [N_WM+1]
    int* wm_cnt = wm_off + N_WM + 1;
    int* wm_bkt = wm_cnt + N_WM;                // [E_WM]
    int* fs_off = wm_bkt + E_WM;                // [N_F+1]
    int* fs_cnt = fs_off + N_F + 1;
    int* fs_bkt = fs_cnt + N_F;                 // [E_F]
    int* bsum_wm = fs_bkt + E_F;                // [64]
    int* bsum_fs = bsum_wm + 64;                // [16]

    ushort_t* h1 = Xb;                 // gemm1 out overwrites Xb (dead)
    ushort_t* F  = Gm;                 // gather out overwrites gemb (dead)
    ushort_t* H  = Gm + 4194304;
    ushort_t* T  = Ee;                 // fstm out overwrites Ee (dead)

    const int* wm_src = wm_ei;
    const int* wm_dst = wm_ei + E_WM;
    const int* f_src  = f_ei;
    const int* f_dst  = f_ei + E_F;

    dim3 blk(256);
    dim3 gW(Gd / TBN, (N_WM + TBM - 1) / TBM);   // 2 x 391
    dim3 gF(Gd / TBN, N_F / TBM);                // 2 x 128
    dim3 gO(PLM / TBN, N_F / TBM);               // 6 x 128

    const int nbW = (N_WM + 1023) / 1024;   // 49
    const int nbF = (N_F + 1023) / 1024;    // 16

    // ===== CSR build =====
    hipMemsetAsync(wm_cnt, 0, N_WM * sizeof(int), stream);
    hipMemsetAsync(fs_cnt, 0, N_F * sizeof(int), stream);
    hist_kernel<<<(E_WM + 255) / 256, blk, 0, stream>>>(wm_dst, wm_cnt, E_WM);
    hist_kernel<<<(E_F + 255) / 256, blk, 0, stream>>>(f_dst, fs_cnt, E_F);
    scan_part1<<<nbW, blk, 0, stream>>>(wm_cnt, bsum_wm, N_WM);
    scan_part1<<<nbF, blk, 0, stream>>>(fs_cnt, bsum_fs, N_F);
    scan_bsums<<<1, 64, 0, stream>>>(bsum_wm, nbW);
    scan_bsums<<<1, 64, 0, stream>>>(bsum_fs, nbF);
    scan_part2<<<nbW, blk, 0, stream>>>(wm_cnt, wm_off, bsum_wm, N_WM, E_WM);
    scan_part2<<<nbF, blk, 0, stream>>>(fs_cnt, fs_off, bsum_fs, N_F, E_F);
    fill_kernel<<<(E_WM + 255) / 256, blk, 0, stream>>>(wm_src, wm_dst, wm_cnt, wm_bkt, E_WM);
    fill_kernel<<<(E_F + 255) / 256, blk, 0, stream>>>(f_src, f_dst, fs_cnt, fs_bkt, E_F);

    // ===== one-time conversions =====
    cvt_bf_kernel<<<(3200000 + 255) / 256, blk, 0, stream>>>(wm_x, Xb, 3200000);
    cvt_bf_kernel<<<(3145728 + 255) / 256, blk, 0, stream>>>(text, Tx, 3145728);
    cvt_bf_kernel<<<1, blk, 0, stream>>>(extra, Exb, 128);
    wt_kernel<<<(65536 + 255) / 256, blk, 0, stream>>>(wm_W1, wt_wm1, 256, 256);
    wt_kernel<<<(65536 + 255) / 256, blk, 0, stream>>>(wm_W2, wt_wm2, 256, 256);
    wt_kernel<<<(65536 + 255) / 256, blk, 0, stream>>>(fs_W1, wt_fs1, 256, 256);
    wt_kernel<<<(65536 + 255) / 256, blk, 0, stream>>>(fs_W2, wt_fs2, 256, 256);
    wt_kernel<<<(262144 + 255) / 256, blk, 0, stream>>>(fc1_W, wt_fc1, 1024, 256);
    wt_kernel<<<(983040 + 255) / 256, blk, 0, stream>>>(fc3_W, wt_fc3, 1280, 768);

    // ===== WM layer 1 =====
    aggregate_kernel<<<(N_WM + 3) / 4, blk, 0, stream>>>(Xb, wm_off, wm_bkt, Ag, N_WM);
    mfma_gemm<0, 1><<<gW, blk, 0, stream>>>(Ag, nullptr, nullptr, wt_wm1, wm_b1,
                                            h1, N_WM, Gd, Gd, 1);
    // ===== WM layer 2 =====
    aggregate_kernel<<<(N_WM + 3) / 4, blk, 0, stream>>>(h1, wm_off, wm_bkt, Ag, N_WM);
    mfma_gemm<0, 1><<<gW, blk, 0, stream>>>(Ag, nullptr, nullptr, wt_wm2, wm_b2,
                                            Gm, N_WM, Gd, Gd, 1);
    // ===== tmp =====
    tmp_kernel<<<N_F / 4, blk, 0, stream>>>(Gm, Exb, t2np, Dt);
    // ===== fc1: Ee = concat(tmp, text) @ fc1_W + b =====
    mfma_gemm<2, 1><<<gF, blk, 0, stream>>>(Dt, Tx, nullptr, wt_fc1, fc1_b,
                                            Ee, N_F, Gd, Gd + PLM, 0);
    // ===== FSTM gather =====
    gather_kernel<<<N_F / 4, blk, 0, stream>>>(Ee, f_ids, F);
    // ===== FSTM layer 1 =====
    aggregate_kernel<<<N_F / 4, blk, 0, stream>>>(F, fs_off, fs_bkt, Ag, N_F);
    mfma_gemm<0, 1><<<gF, blk, 0, stream>>>(Ag, nullptr, nullptr, wt_fs1, fs_b1,
                                            H, N_F, Gd, Gd, 1);
    // ===== FSTM layer 2 =====
    aggregate_kernel<<<N_F / 4, blk, 0, stream>>>(H, fs_off, fs_bkt, Ag, N_F);
    mfma_gemm<0, 1><<<gF, blk, 0, stream>>>(Ag, nullptr, nullptr, wt_fs2, fs_b2,
                                            T, N_F, Gd, Gd, 1);
    // ===== fc3: out = concat(text, tmp, temporal) @ fc3_W + b (fp32 out) =====
    mfma_gemm<3, 0><<<gO, blk, 0, stream>>>(Tx, Dt, T, wt_fc3, fc3_b,
                                            out, N_F, PLM, PLM + 2 * Gd, 0);
}